// Round 1
// 9829.173 us; speedup vs baseline: 1.7235x; 1.7235x over previous
//
#include <hip/hip_runtime.h>
#include <math.h>
#include <stddef.h>

#define E 1024
#define NH 16
#define DH 64
#define HID 4096
#define NLAYER 6
#define VV 32000
#define BB 4
#define SS 512
#define TT 512
#define MROWS (BB * SS)   // 2048 rows for both encoder and decoder streams

// ---------------------------------------------------------------------------
// Embedding + sinusoidal positional encoding
// ---------------------------------------------------------------------------
__global__ __launch_bounds__(256) void embed_kernel(const int* __restrict__ tok,
                                                    const float* __restrict__ emb,
                                                    float* __restrict__ out,
                                                    int seqlen, float scale) {
    int row = blockIdx.x;
    int pos = row % seqlen;
    int t = tok[row];
    const float* erow = emb + (size_t)t * E;
    float* orow = out + (size_t)row * E;
    for (int e = threadIdx.x; e < E; e += blockDim.x) {
        int half = e >> 1;
        float freq = expf((float)(2 * half) * (-9.210340371976184f / (float)E)); // -ln(10000)/E
        float ang = (float)pos * freq;
        float pe = (e & 1) ? cosf(ang) : sinf(ang);
        orow[e] = erow[e] * scale + pe;
    }
}

// ---------------------------------------------------------------------------
// Row LayerNorm over E=1024, one block (256 thr) per row, 4 elems/thread
// ---------------------------------------------------------------------------
__global__ __launch_bounds__(256) void ln_kernel(const float* __restrict__ in,
                                                 const float* __restrict__ gamma,
                                                 const float* __restrict__ beta,
                                                 float* __restrict__ out) {
    int row = blockIdx.x;
    const float* xr = in + (size_t)row * E;
    float* orow = out + (size_t)row * E;
    int tid = threadIdx.x;
    float v[4];
    float s = 0.f;
#pragma unroll
    for (int i = 0; i < 4; ++i) { v[i] = xr[tid + 256 * i]; s += v[i]; }
    __shared__ float sh[4];
#pragma unroll
    for (int o = 32; o > 0; o >>= 1) s += __shfl_down(s, o);
    int wave = tid >> 6;
    if ((tid & 63) == 0) sh[wave] = s;
    __syncthreads();
    float mu = (sh[0] + sh[1] + sh[2] + sh[3]) * (1.f / E);
    float sq = 0.f;
#pragma unroll
    for (int i = 0; i < 4; ++i) { float d = v[i] - mu; sq += d * d; }
    __syncthreads();
#pragma unroll
    for (int o = 32; o > 0; o >>= 1) sq += __shfl_down(sq, o);
    if ((tid & 63) == 0) sh[wave] = sq;
    __syncthreads();
    float var = (sh[0] + sh[1] + sh[2] + sh[3]) * (1.f / E);
    float rstd = rsqrtf(var + 1e-5f);
#pragma unroll
    for (int i = 0; i < 4; ++i) {
        int c = tid + 256 * i;
        orow[c] = (v[i] - mu) * rstd * gamma[c] + beta[c];
    }
}

// ---------------------------------------------------------------------------
// Split-bf16 MFMA GEMM: C = A(M,K) @ W(K,N) [+bias][relu][+res]
// fp32 emulated as hi/lo bf16 pair, 3 MFMA passes (hi*hi + hi*lo + lo*hi).
// 128x128 tile, BK=32, 256 threads = 4 waves (2x2), 64x64 per wave,
// 4x4 fragments of mfma_f32_16x16x32_bf16 per wave.
// A staged fp32 via global_load_lds (linear dest, XOR-swizzled source);
// B reg-staged transposed into Bs[n][k] (same XOR swizzle) so fragment
// k-reads are contiguous ds_read_b128. Swizzle: chunk16 ^= (row>>2)&7.
// Requires M%128==0, N%128==0, K%32==0 (true at all call sites).
// ---------------------------------------------------------------------------
#define BM 128
#define BN 128

typedef __attribute__((ext_vector_type(8))) short bf16x8;
typedef __attribute__((ext_vector_type(4))) float f32x4;

typedef __attribute__((address_space(3))) void as3_void;
typedef const __attribute__((address_space(1))) void as1_cvoid;

__device__ __forceinline__ unsigned f2u(float f) { union { float f; unsigned u; } v; v.f = f; return v.u; }
__device__ __forceinline__ float u2f(unsigned u) { union { unsigned u; float f; } v; v.u = u; return v.f; }

// two fp32 -> packed bf16 hi-pair / lo-pair words (truncation split; a = hi+lo exact)
__device__ __forceinline__ void hilo2(float a, float b, unsigned& hw, unsigned& lw) {
    unsigned ua = f2u(a), ub = f2u(b);
    unsigned ha = ua & 0xffff0000u, hb = ub & 0xffff0000u;
    hw = hb | (ha >> 16);
    float la = a - u2f(ha);
    float lb = b - u2f(hb);
    lw = (f2u(lb) & 0xffff0000u) | (f2u(la) >> 16);
}

union frag_u { unsigned w[4]; bf16x8 v; };

__device__ __forceinline__ void cvt_frag(const float4 q0, const float4 q1,
                                         bf16x8& hi, bf16x8& lo) {
    frag_u H, L;
    hilo2(q0.x, q0.y, H.w[0], L.w[0]);
    hilo2(q0.z, q0.w, H.w[1], L.w[1]);
    hilo2(q1.x, q1.y, H.w[2], L.w[2]);
    hilo2(q1.z, q1.w, H.w[3], L.w[3]);
    hi = H.v;
    lo = L.v;
}

__global__ __launch_bounds__(256) void gemm_mfma_kernel(
    const float* __restrict__ A, const float* __restrict__ W,
    const float* __restrict__ bias, const float* __restrict__ res,
    float* __restrict__ C, int M, int N, int K, int relu,
    size_t strideA, size_t strideW, size_t strideC) {
    int z = blockIdx.z;
    A += (size_t)z * strideA;
    W += (size_t)z * strideW;
    C += (size_t)z * strideC;

    __shared__ __align__(16) float As[128 * 32];  // swizzled [m][k] fp32
    __shared__ __align__(16) float Bs[128 * 32];  // swizzled [n][k] fp32 (transposed)

    const int tid = threadIdx.x;
    const int lane = tid & 63;
    const int wid = tid >> 6;
    const int wr = wid >> 1, wc = wid & 1;
    const int l16 = lane & 15, g = lane >> 4;

    const int m0 = blockIdx.y * BM;
    const int n0 = blockIdx.x * BN;

    f32x4 acc[4][4];
    const f32x4 zero4 = {0.f, 0.f, 0.f, 0.f};
#pragma unroll
    for (int i = 0; i < 4; ++i)
#pragma unroll
        for (int j = 0; j < 4; ++j) acc[i][j] = zero4;

    // A staging decode: LDS linear idx lin -> (m = lin>>3, phys chunk = lin&7),
    // logical chunk c = (lin&7) ^ ((m>>2)&7); source = A[m0+m][k0 + 4c]
    size_t aoff[4];
    float* alds[4];
#pragma unroll
    for (int p = 0; p < 4; ++p) {
        int lin = p * 256 + tid;
        int m = lin >> 3;
        int c = (lin & 7) ^ ((m >> 2) & 7);
        aoff[p] = (size_t)(m0 + m) * K + 4 * c;
        alds[p] = &As[lin * 4];
    }
    const int bk = tid >> 5;          // 0..7 (k row within group of 8)
    const int bn4 = (tid & 31) * 4;   // col base

    for (int k0 = 0; k0 < K; k0 += 32) {
        // B global loads first (overlap with previous iteration's tail)
        float4 bld[4];
#pragma unroll
        for (int p = 0; p < 4; ++p)
            bld[p] = *(const float4*)&W[(size_t)(k0 + p * 8 + bk) * N + n0 + bn4];

        __syncthreads();  // all waves done reading LDS from previous step

        // A: direct global -> LDS (linear dest, pre-swizzled source)
#pragma unroll
        for (int p = 0; p < 4; ++p)
            __builtin_amdgcn_global_load_lds((as1_cvoid*)(A + aoff[p] + k0),
                                             (as3_void*)alds[p], 16, 0, 0);

        // B: transposed swizzled scatter into Bs[n][k]
#pragma unroll
        for (int p = 0; p < 4; ++p) {
            int k = p * 8 + bk;
            float vv4[4] = {bld[p].x, bld[p].y, bld[p].z, bld[p].w};
#pragma unroll
            for (int c2 = 0; c2 < 4; ++c2) {
                int n = bn4 + c2;
                int ch = (k >> 2) ^ ((n >> 2) & 7);
                Bs[n * 32 + ch * 4 + (k & 3)] = vv4[c2];
            }
        }
        __syncthreads();  // compiler emits vmcnt(0)+lgkmcnt(0) drain here

        // B fragments for this wave's 4 column tiles (k = g*8 .. g*8+7)
        bf16x8 bhi[4], blo[4];
#pragma unroll
        for (int j = 0; j < 4; ++j) {
            int n = wc * 64 + j * 16 + l16;
            int sw = (n >> 2) & 7;
            const float4 q0 = *(const float4*)&Bs[n * 32 + (((2 * g) ^ sw) << 2)];
            const float4 q1 = *(const float4*)&Bs[n * 32 + (((2 * g + 1) ^ sw) << 2)];
            cvt_frag(q0, q1, bhi[j], blo[j]);
        }
        // A fragments + 3-pass MFMA
#pragma unroll
        for (int i = 0; i < 4; ++i) {
            int m = wr * 64 + i * 16 + l16;
            int sw = (m >> 2) & 7;
            const float4 q0 = *(const float4*)&As[m * 32 + (((2 * g) ^ sw) << 2)];
            const float4 q1 = *(const float4*)&As[m * 32 + (((2 * g + 1) ^ sw) << 2)];
            bf16x8 ahi, alo;
            cvt_frag(q0, q1, ahi, alo);
#pragma unroll
            for (int j = 0; j < 4; ++j)
                acc[i][j] = __builtin_amdgcn_mfma_f32_16x16x32_bf16(ahi, bhi[j], acc[i][j], 0, 0, 0);
#pragma unroll
            for (int j = 0; j < 4; ++j)
                acc[i][j] = __builtin_amdgcn_mfma_f32_16x16x32_bf16(ahi, blo[j], acc[i][j], 0, 0, 0);
#pragma unroll
            for (int j = 0; j < 4; ++j)
                acc[i][j] = __builtin_amdgcn_mfma_f32_16x16x32_bf16(alo, bhi[j], acc[i][j], 0, 0, 0);
        }
    }

    // Epilogue. C/D layout (m89-verified): col = lane&15, row = (lane>>4)*4 + reg
    float bs4[4];
#pragma unroll
    for (int j = 0; j < 4; ++j) {
        int ncol = n0 + wc * 64 + j * 16 + l16;
        bs4[j] = bias ? bias[ncol] : 0.f;
    }
#pragma unroll
    for (int i = 0; i < 4; ++i) {
#pragma unroll
        for (int r = 0; r < 4; ++r) {
            int m = m0 + wr * 64 + i * 16 + g * 4 + r;
            size_t crow = (size_t)m * N;
#pragma unroll
            for (int j = 0; j < 4; ++j) {
                int ncol = n0 + wc * 64 + j * 16 + l16;
                float val = acc[i][j][r] + bs4[j];
                if (relu) val = fmaxf(val, 0.f);
                if (res) val += res[crow + ncol];
                C[crow + ncol] = val;
            }
        }
    }
}

// ---------------------------------------------------------------------------
// Attention scores: Sc[bh, q, k] = dot(Q[b,q,h,:], K[b,k,h,:]) / 32  (masked)
// ---------------------------------------------------------------------------
__global__ __launch_bounds__(256) void scores_kernel(
    const float* __restrict__ Qb, const float* __restrict__ Kb,
    const int* __restrict__ qtok, const int* __restrict__ ktok,
    float* __restrict__ Sc, int Tq, int Tk, int mode) {
    int bh = blockIdx.z;
    int b = bh >> 4;
    int h = bh & 15;
    int q0 = blockIdx.x * 64;
    int k0 = blockIdx.y * 64;
    __shared__ float Qs[64][68];
    __shared__ float Ks[64][68];
    int tid = threadIdx.x;
    int f = tid & 15, r0 = tid >> 4;
#pragma unroll
    for (int it = 0; it < 4; ++it) {
        int rr = r0 + it * 16;
        *(float4*)&Qs[rr][f * 4] =
            *(const float4*)&Qb[(size_t)(b * Tq + q0 + rr) * E + h * 64 + f * 4];
        *(float4*)&Ks[rr][f * 4] =
            *(const float4*)&Kb[(size_t)(b * Tk + k0 + rr) * E + h * 64 + f * 4];
    }
    __syncthreads();
    int tx = tid & 15, ty = tid >> 4;
    float acc[4][4];
#pragma unroll
    for (int i = 0; i < 4; ++i)
#pragma unroll
        for (int j = 0; j < 4; ++j) acc[i][j] = 0.f;
#pragma unroll 4
    for (int d4 = 0; d4 < 16; ++d4) {
        float4 qa[4], kb[4];
#pragma unroll
        for (int i = 0; i < 4; ++i) qa[i] = *(const float4*)&Qs[ty * 4 + i][d4 * 4];
#pragma unroll
        for (int j = 0; j < 4; ++j) kb[j] = *(const float4*)&Ks[tx * 4 + j][d4 * 4];
#pragma unroll
        for (int i = 0; i < 4; ++i)
#pragma unroll
            for (int j = 0; j < 4; ++j)
                acc[i][j] += qa[i].x * kb[j].x + qa[i].y * kb[j].y +
                             qa[i].z * kb[j].z + qa[i].w * kb[j].w;
    }
    const float scale = 1.0f / 32.0f;  // 1/sqrt(E)
#pragma unroll
    for (int i = 0; i < 4; ++i) {
        int q = q0 + ty * 4 + i;
        bool qv = qtok[b * Tq + q] != 0;
        float tmp[4];
#pragma unroll
        for (int j = 0; j < 4; ++j) {
            int k = k0 + tx * 4 + j;
            bool ok;
            if (mode == 0)      ok = qv && (ktok[b * Tk + k] != 0);
            else if (mode == 1) ok = qv && (q >= k);
            else                ok = qv;
            tmp[j] = ok ? acc[i][j] * scale : -10000.0f;
        }
        float4 o = make_float4(tmp[0], tmp[1], tmp[2], tmp[3]);
        *(float4*)&Sc[((size_t)bh * Tq + q) * Tk + k0 + tx * 4] = o;
    }
}

// ---------------------------------------------------------------------------
// Row softmax over Tk=512, one block per row, in place
// ---------------------------------------------------------------------------
__global__ __launch_bounds__(256) void softmax_kernel(float* __restrict__ Sc, int Tk) {
    size_t row = blockIdx.x;
    float* p = Sc + row * (size_t)Tk;
    int tid = threadIdx.x;
    float v0 = p[tid], v1 = p[tid + 256];
    float m = fmaxf(v0, v1);
    __shared__ float sh[4];
#pragma unroll
    for (int o = 32; o > 0; o >>= 1) m = fmaxf(m, __shfl_down(m, o));
    int wave = tid >> 6;
    if ((tid & 63) == 0) sh[wave] = m;
    __syncthreads();
    m = fmaxf(fmaxf(sh[0], sh[1]), fmaxf(sh[2], sh[3]));
    float e0 = __expf(v0 - m), e1 = __expf(v1 - m);
    float s = e0 + e1;
    __syncthreads();
#pragma unroll
    for (int o = 32; o > 0; o >>= 1) s += __shfl_down(s, o);
    if ((tid & 63) == 0) sh[wave] = s;
    __syncthreads();
    float inv = 1.f / (sh[0] + sh[1] + sh[2] + sh[3]);
    p[tid] = e0 * inv;
    p[tid + 256] = e1 * inv;
}

// ---------------------------------------------------------------------------
// ctx: out[b*Tq+q, h*64+d] = res[same] + sum_k P[bh,q,k] * V[b*Tk+k, h*64+d]
// ---------------------------------------------------------------------------
__global__ __launch_bounds__(256) void ctx_kernel(
    const float* __restrict__ P, const float* __restrict__ Vb,
    const float* __restrict__ res, float* __restrict__ out,
    int Tq, int Tk) {
    int b = blockIdx.z, h = blockIdx.y;
    int q0 = blockIdx.x * 64;
    int bh = b * NH + h;
    __shared__ float Ps[64][68];  // transposed: Ps[k][q]
    __shared__ float Vs[64][68];  // Vs[k][d]
    int tid = threadIdx.x;
    int f = tid & 15, r0 = tid >> 4;
    int tx = tid & 15, ty = tid >> 4;
    float acc[4][4];
#pragma unroll
    for (int i = 0; i < 4; ++i)
#pragma unroll
        for (int j = 0; j < 4; ++j) acc[i][j] = 0.f;

    for (int kc = 0; kc < Tk; kc += 64) {
        __syncthreads();
#pragma unroll
        for (int it = 0; it < 4; ++it) {
            int rr = r0 + it * 16;
            float4 pv = *(const float4*)&P[((size_t)bh * Tq + q0 + rr) * Tk + kc + f * 4];
            Ps[f * 4 + 0][rr] = pv.x;
            Ps[f * 4 + 1][rr] = pv.y;
            Ps[f * 4 + 2][rr] = pv.z;
            Ps[f * 4 + 3][rr] = pv.w;
            *(float4*)&Vs[rr][f * 4] =
                *(const float4*)&Vb[(size_t)(b * Tk + kc + rr) * E + h * 64 + f * 4];
        }
        __syncthreads();
#pragma unroll
        for (int kk = 0; kk < 64; ++kk) {
            float4 pa = *(const float4*)&Ps[kk][ty * 4];
            float4 vb = *(const float4*)&Vs[kk][tx * 4];
            float am[4] = {pa.x, pa.y, pa.z, pa.w};
            float bm[4] = {vb.x, vb.y, vb.z, vb.w};
#pragma unroll
            for (int i = 0; i < 4; ++i)
#pragma unroll
                for (int j = 0; j < 4; ++j) acc[i][j] += am[i] * bm[j];
        }
    }
#pragma unroll
    for (int i = 0; i < 4; ++i) {
        int q = q0 + ty * 4 + i;
        size_t orow = (size_t)(b * Tq + q) * E + h * 64;
        float tmp[4];
#pragma unroll
        for (int j = 0; j < 4; ++j) tmp[j] = res[orow + tx * 4 + j] + acc[i][j];
        float4 o = make_float4(tmp[0], tmp[1], tmp[2], tmp[3]);
        *(float4*)&out[orow + tx * 4] = o;
    }
}

// ---------------------------------------------------------------------------
extern "C" void kernel_launch(void* const* d_in, const int* in_sizes, int n_in,
                              void* d_out, int out_size, void* d_ws, size_t ws_size,
                              hipStream_t stream) {
    const int* src = (const int*)d_in[0];
    const int* tgt = (const int*)d_in[1];
    const float* emb_enc = (const float*)d_in[2];
    const float* emb_dec = (const float*)d_in[3];
    const float* enc_qkv = (const float*)d_in[4];
    const float* enc_w1 = (const float*)d_in[5];
    const float* enc_b1 = (const float*)d_in[6];
    const float* enc_w2 = (const float*)d_in[7];
    const float* enc_b2 = (const float*)d_in[8];
    const float* enc_ln_g = (const float*)d_in[9];
    const float* enc_ln_b = (const float*)d_in[10];
    const float* dec_qkv_self = (const float*)d_in[11];
    const float* dec_qkv_cross = (const float*)d_in[12];
    const float* dec_w1 = (const float*)d_in[13];
    const float* dec_b1 = (const float*)d_in[14];
    const float* dec_w2 = (const float*)d_in[15];
    const float* dec_b2 = (const float*)d_in[16];
    const float* dec_ln_g = (const float*)d_in[17];
    const float* dec_ln_b = (const float*)d_in[18];
    const float* fin_ln_g = (const float*)d_in[19];
    const float* fin_ln_b = (const float*)d_in[20];
    const float* out_w = (const float*)d_in[21];
    const float* out_b = (const float*)d_in[22];
    float* out = (float*)d_out;

    const size_t BSE = (size_t)BB * SS * E;        // 2,097,152 floats
    const size_t BSH = (size_t)BB * SS * HID;      // 8,388,608
    const size_t SCN = (size_t)BB * NH * SS * TT;  // 16,777,216

    float* ws = (float*)d_ws;
    float* x = ws;            // encoder stream / enc_out
    float* y = x + BSE;       // decoder stream
    float* n = y + BSE;       // layernorm output (residual source)
    float* a = n + BSE;       // attention output + residual
    float* q = a + BSE;
    float* k = q + BSE;
    float* v = k + BSE;
    float* big = v + BSE;     // shared by FFN hidden (8M) and scores (16M)
    float* h = big;
    float* sc = big;

    dim3 blk(256);
    embed_kernel<<<BB * SS, blk, 0, stream>>>(src, emb_enc, x, SS, 32.0f);
    embed_kernel<<<BB * TT, blk, 0, stream>>>(tgt, emb_dec, y, TT, 1.0f);

    dim3 gQKV(E / BN, MROWS / BM, 3);
    dim3 gQ(E / BN, MROWS / BM, 1);
    dim3 gKV(E / BN, MROWS / BM, 2);
    dim3 gFF1(HID / BN, MROWS / BM, 1);
    dim3 gFF2(E / BN, MROWS / BM, 1);
    dim3 gOut(VV / BN, MROWS / BM, 1);
    dim3 gSc(SS / 64, SS / 64, BB * NH);
    dim3 gCx(SS / 64, NH, BB);

    // ---------------- encoder ----------------
    for (int i = 0; i < NLAYER; ++i) {
        const float* g = enc_ln_g + i * E;
        const float* be = enc_ln_b + i * E;
        const float* wqkv = enc_qkv + (size_t)i * 3 * E * E;
        ln_kernel<<<MROWS, blk, 0, stream>>>(x, g, be, n);
        gemm_mfma_kernel<<<gQKV, blk, 0, stream>>>(n, wqkv, nullptr, nullptr, q,
                                                   MROWS, E, E, 0, 0, (size_t)E * E, BSE);
        scores_kernel<<<gSc, blk, 0, stream>>>(q, k, src, src, sc, SS, SS, 0);
        softmax_kernel<<<BB * NH * SS, blk, 0, stream>>>(sc, SS);
        ctx_kernel<<<gCx, blk, 0, stream>>>(sc, v, n, a, SS, SS);
        ln_kernel<<<MROWS, blk, 0, stream>>>(a, g, be, n);
        gemm_mfma_kernel<<<gFF1, blk, 0, stream>>>(n, enc_w1 + (size_t)i * E * HID,
                                                   enc_b1 + i * HID, nullptr, h,
                                                   MROWS, HID, E, 1, 0, 0, 0);
        gemm_mfma_kernel<<<gFF2, blk, 0, stream>>>(h, enc_w2 + (size_t)i * HID * E,
                                                   enc_b2 + i * E, n, x,
                                                   MROWS, E, HID, 0, 0, 0, 0);
    }
    // ---------------- decoder ----------------
    for (int i = 0; i < NLAYER; ++i) {
        const float* g = dec_ln_g + i * E;
        const float* be = dec_ln_b + i * E;
        const float* wself = dec_qkv_self + (size_t)i * 3 * E * E;
        const float* wcross = dec_qkv_cross + (size_t)i * 3 * E * E;
        // self-attention
        ln_kernel<<<MROWS, blk, 0, stream>>>(y, g, be, n);
        gemm_mfma_kernel<<<gQKV, blk, 0, stream>>>(n, wself, nullptr, nullptr, q,
                                                   MROWS, E, E, 0, 0, (size_t)E * E, BSE);
        scores_kernel<<<gSc, blk, 0, stream>>>(q, k, tgt, tgt, sc, TT, TT, 1);
        softmax_kernel<<<BB * NH * TT, blk, 0, stream>>>(sc, TT);
        ctx_kernel<<<gCx, blk, 0, stream>>>(sc, v, n, a, TT, TT);
        ln_kernel<<<MROWS, blk, 0, stream>>>(a, g, be, n);
        // cross-attention: Q from n, K/V from enc_out (x)
        gemm_mfma_kernel<<<gQ, blk, 0, stream>>>(n, wcross, nullptr, nullptr, q,
                                                 MROWS, E, E, 0, 0, 0, 0);
        gemm_mfma_kernel<<<gKV, blk, 0, stream>>>(x, wcross + (size_t)E * E, nullptr, nullptr, k,
                                                  MROWS, E, E, 0, 0, (size_t)E * E, BSE);
        scores_kernel<<<gSc, blk, 0, stream>>>(q, k, tgt, nullptr, sc, TT, SS, 2);
        softmax_kernel<<<BB * NH * TT, blk, 0, stream>>>(sc, SS);
        ctx_kernel<<<gCx, blk, 0, stream>>>(sc, v, n, a, TT, SS);
        ln_kernel<<<MROWS, blk, 0, stream>>>(a, g, be, n);
        // FFN
        gemm_mfma_kernel<<<gFF1, blk, 0, stream>>>(n, dec_w1 + (size_t)i * E * HID,
                                                   dec_b1 + i * HID, nullptr, h,
                                                   MROWS, HID, E, 1, 0, 0, 0);
        gemm_mfma_kernel<<<gFF2, blk, 0, stream>>>(h, dec_w2 + (size_t)i * HID * E,
                                                   dec_b2 + i * E, n, y,
                                                   MROWS, E, HID, 0, 0, 0, 0);
    }
    // ---------------- final LN + logits ----------------
    ln_kernel<<<MROWS, blk, 0, stream>>>(y, fin_ln_g, fin_ln_b, n);
    gemm_mfma_kernel<<<gOut, blk, 0, stream>>>(n, out_w, out_b, nullptr, out,
                                               MROWS, VV, E, 0, 0, 0, 0);
}